// Round 5
// baseline (59.302 us; speedup 1.0000x reference)
//
#include <hip/hip_runtime.h>
#include <math.h>

// NCEAverage forward, MI355X — 3-dispatch fused pipeline.
// d_out layout (float32):
//   [0, C0)               : out_feature_p_n (B x K+1), C0 = B*(K+1)
//   [C0, C0+R*128)        : feature_clu_all (R x 128)
//   [C0+R*128, C0+R*129)  : gt_clu_all (R)
// R derived on host from out_size.
//
// Stage A: counts(64-granular) | featn | pos | bucket
// Stage B: sims tiles (first, 3/CU LDS-bound) || gather (per-64-group blocks,
//          self-offset from counts, row-parallel: 8 half-waves x unroll-2)
// Stage D: redundant deterministic Z-reduce + out0 scale

#define TINV 14.2857142857142857f   // 1/0.07
#define JT 64
#define BT 32

__device__ __forceinline__ float wredsum64(float v) {
#pragma unroll
  for (int m = 32; m > 0; m >>= 1) v += __shfl_xor(v, m, 64);
  return v;
}

// ================= Stage A: counts | featn | pos | bucket ===================
__global__ __launch_bounds__(256) void k_stageA(
    const float* __restrict__ feat, const int* __restrict__ label,
    const float* __restrict__ mfg, const float* __restrict__ pg,
    const float* __restrict__ mfm, const float* __restrict__ pm,
    const int* __restrict__ idxpg, const int* __restrict__ idxpm,
    float* __restrict__ outp, long long cluTail, long long gtTail,
    int* __restrict__ bucket, int* __restrict__ n0p,
    int* __restrict__ cg64, int* __restrict__ cm64,
    float* __restrict__ posPartials,
    int B, int K1, int G, int M,
    int nCountBlk, int nFeatBlk, int nPosBlk) {
  int bid = blockIdx.x, t = threadIdx.x;

  if (bid < nCountBlk) {  // ---- 64-granular selection counts (both banks)
    int i = bid * 256 + t;
    int a = (i < G) && (pg[i] > 0.5f);
    int b = (i < M) && (pm[i] > 0.6f);
    unsigned long long ba = __ballot(a), bb = __ballot(b);
    int lane = t & 63, w = t >> 6;
    if (lane == 0) {
      cg64[bid * 4 + w] = __popcll(ba);
      cm64[bid * 4 + w] = __popcll(bb);
    }
    return;
  }
  bid -= nCountBlk;

  if (bid < nFeatBlk) {  // ---- normalize feat rows into d_out tail + gt
    int gid = bid * 256 + t;
    int w = gid >> 6, lane = gid & 63;
    if (w < B) {
      float2 v = ((const float2*)feat)[(long long)w * 64 + lane];
      float sq = wredsum64(v.x * v.x + v.y * v.y);
      float inv = rsqrtf(sq);
      ((float2*)(outp + cluTail))[(long long)w * 64 + lane] =
          make_float2(v.x * inv, v.y * inv);
      if (lane == 0) outp[gtTail + w] = (float)label[w];
    }
    return;
  }
  bid -= nFeatBlk;

  if (bid < nPosBlk) {  // ---- positives column (norms inline)
    __shared__ float ps[4];
    int gid = bid * 256 + t;
    int w = gid >> 6, lane = gid & 63, lw = t >> 6;
    float e = 0.f;
    if (w < B) {
      int lab = label[w];
      const float* bank = lab ? mfm : mfg;
      long long row = lab ? idxpm[0] : idxpg[0];
      float2 wv = ((const float2*)(bank + row * 128))[lane];
      float2 fv = ((const float2*)feat)[(long long)w * 64 + lane];
      float dot = wredsum64(fv.x * wv.x + fv.y * wv.y);
      float sqw = wredsum64(wv.x * wv.x + wv.y * wv.y);
      float sqf = wredsum64(fv.x * fv.x + fv.y * fv.y);
      e = expf(dot * rsqrtf(sqw) * rsqrtf(sqf) * TINV);
      if (lane == 0) outp[(long long)w * K1] = e;
    }
    if (lane == 0) ps[lw] = e;
    __syncthreads();
    if (t == 0) posPartials[bid] = ps[0] + ps[1] + ps[2] + ps[3];
    return;
  }

  // ---- bucket: stable partition of batch by label (B <= 512)
  {
    __shared__ int sc[512];
    int t2 = t + 256;
    int m0 = (t < B) ? (label[t] == 0 ? 1 : 0) : 0;
    int m1 = (t2 < B) ? (label[t2] == 0 ? 1 : 0) : 0;
    sc[t] = m0; sc[t2] = m1;
    __syncthreads();
    for (int off = 1; off < 512; off <<= 1) {
      int u0 = (t >= off) ? sc[t - off] : 0;
      int u1 = (t2 >= off) ? sc[t2 - off] : 0;
      __syncthreads();
      sc[t] += u0; sc[t2] += u1;
      __syncthreads();
    }
    int n0 = (B > 0) ? sc[B - 1] : 0;
    if (t < B) {
      int incl = sc[t];
      if (m0) bucket[incl - 1] = t; else bucket[n0 + t - incl] = t;
    }
    if (t2 < B) {
      int incl = sc[t2];
      if (m1) bucket[incl - 1] = t2; else bucket[n0 + t2 - incl] = t2;
    }
    if (t == 0) *n0p = n0;
  }
}

// ================= Stage B: sims tiles | gather groups ======================
__global__ __launch_bounds__(256) void k_stageB(
    const float* __restrict__ featn, const int* __restrict__ bucket,
    const int* __restrict__ n0ptr,
    const float* __restrict__ mfg, const float* __restrict__ mfm,
    const float* __restrict__ pg, const float* __restrict__ pm,
    const int* __restrict__ idxng, const int* __restrict__ idxnm,
    const int* __restrict__ cg64, const int* __restrict__ cm64,
    float* __restrict__ out0, float* __restrict__ partials,
    float* __restrict__ outp, long long cluBase, long long gtBase,
    int B, int K, int K1, int G, int M, int NG64, int simsGx, int nSimsBlk) {
  int t = threadIdx.x;

  if ((int)blockIdx.x >= nSimsBlk) {
    // ---- gather: one block per (bank, 64-candidate group). Destination
    // offset from L2-hot 64-granular counts; rows processed 16-wide/iter.
    int gb = (int)blockIdx.x - nSimsBlk;
    int bankId = gb / NG64;
    int g = gb - bankId * NG64;
    const float* probs = bankId ? pm : pg;
    const float* rows  = bankId ? mfm : mfg;
    float thr = bankId ? 0.6f : 0.5f;
    int Nelem = bankId ? M : G;
    int lane = t & 63, w = t >> 6;

    int s = 0;
    for (int j = t; j < NG64; j += 256) {
      if (bankId == 0) {
        if (j < g) s += cg64[j];
      } else {
        s += cg64[j];
        if (j < g) s += cm64[j];
      }
    }
#pragma unroll
    for (int m = 32; m > 0; m >>= 1) s += __shfl_xor(s, m, 64);

    __shared__ int red[4];
    __shared__ int selRow[64];
    if (lane == 0) red[w] = s;

    int c = g * 64 + lane;
    int f = (c < Nelem) && (probs[c] > thr);
    unsigned long long mb = __ballot(f);
    if (w == 0) {
      unsigned long long below = lane ? ((~0ull) >> (64 - lane)) : 0ull;
      if (f) selRow[__popcll(mb & below)] = c;
    }
    __syncthreads();
    int S = __popcll(mb);
    if (S == 0) return;
    long long off = (long long)red[0] + red[1] + red[2] + red[3];

    float labv = (float)bankId;
    int hw = t >> 5, l = t & 31;
    for (int r0 = hw * 2; r0 < S; r0 += 16) {
      int r1 = r0 + 1;
      int src0 = selRow[r0];
      bool has1 = (r1 < S);
      int src1 = has1 ? selRow[r1] : src0;
      float4 v0 = ((const float4*)(rows + (long long)src0 * 128))[l];
      float4 v1 = ((const float4*)(rows + (long long)src1 * 128))[l];
      float sq0 = v0.x * v0.x + v0.y * v0.y + v0.z * v0.z + v0.w * v0.w;
      float sq1 = v1.x * v1.x + v1.y * v1.y + v1.z * v1.z + v1.w * v1.w;
#pragma unroll
      for (int m = 16; m > 0; m >>= 1) {
        sq0 += __shfl_xor(sq0, m, 64);
        sq1 += __shfl_xor(sq1, m, 64);
      }
      float i0 = rsqrtf(sq0), i1 = rsqrtf(sq1);
      long long d0 = off + r0;
      ((float4*)(outp + cluBase + d0 * 128))[l] =
          make_float4(v0.x * i0, v0.y * i0, v0.z * i0, v0.w * i0);
      if (l == 0) outp[gtBase + d0] = labv;
      if (has1) {
        long long d1 = off + r1;
        ((float4*)(outp + cluBase + d1 * 128))[l] =
            make_float4(v1.x * i1, v1.y * i1, v1.z * i1, v1.w * i1);
        if (l == 0) outp[gtBase + d1] = labv;
      }
    }
    return;
  }

  // ---- sims tile: 64 j x 32 b, label-pure blocks, inline w-norms
  __shared__ float4 wl[JT][33];
  __shared__ float4 fl[BT][33];
  __shared__ float invw[JT];
  __shared__ float bs[4];
  int pidx = (int)blockIdx.x;
  int bx = pidx % simsGx, by = pidx / simsGx;
  int n0 = *n0ptr;
  int nb0 = (n0 + BT - 1) / BT;
  int lab, p0, cnt;
  if (by < nb0) {
    lab = 0; p0 = by * BT; cnt = min(BT, n0 - p0);
  } else {
    int k = by - nb0; p0 = n0 + k * BT;
    int n1 = B - n0; cnt = min(BT, n1 - k * BT); lab = 1;
  }
  if (cnt <= 0) { if (t == 0) partials[pidx] = 0.f; return; }
  const float* bank = lab == 0 ? mfm : mfg;
  const int* idxN   = lab == 0 ? idxnm : idxng;
  int j0 = bx * JT;

#pragma unroll
  for (int q = 0; q < 8; q++) {
    int lin = q * 256 + t;
    int row = lin >> 5, col = lin & 31;
    long long srow = idxN[j0 + row];
    wl[row][col] = ((const float4*)(bank + srow * 128))[col];
  }
#pragma unroll
  for (int q = 0; q < 4; q++) {
    int lin = q * 256 + t;
    int row = lin >> 5, col = lin & 31;
    float4 v = make_float4(0.f, 0.f, 0.f, 0.f);
    if (row < cnt) {
      int bg = bucket[p0 + row];
      v = ((const float4*)(featn + (long long)bg * 128))[col];
    }
    fl[row][col] = v;
  }
  __syncthreads();

  {  // inline inverse norms of the staged w tile (4 threads per row)
    int r = t >> 2, q = t & 3;
    float ss = 0.f;
#pragma unroll
    for (int c = 0; c < 8; c++) {
      float4 v = wl[r][q * 8 + c];
      ss += v.x * v.x + v.y * v.y + v.z * v.z + v.w * v.w;
    }
    ss += __shfl_xor(ss, 1, 64);
    ss += __shfl_xor(ss, 2, 64);
    if (q == 0) invw[r] = rsqrtf(ss);
  }
  __syncthreads();

  int tj = t & 15, tb = t >> 4;
  float acc[4][2];
#pragma unroll
  for (int a = 0; a < 4; a++)
#pragma unroll
    for (int b = 0; b < 2; b++) acc[a][b] = 0.f;

#pragma unroll 4
  for (int i = 0; i < 32; i++) {
    float4 w0 = wl[tj][i];
    float4 w1 = wl[tj + 16][i];
    float4 w2 = wl[tj + 32][i];
    float4 w3 = wl[tj + 48][i];
    float4 f0 = fl[tb][i];
    float4 f1 = fl[tb + 16][i];
    acc[0][0] += w0.x*f0.x + w0.y*f0.y + w0.z*f0.z + w0.w*f0.w;
    acc[1][0] += w1.x*f0.x + w1.y*f0.y + w1.z*f0.z + w1.w*f0.w;
    acc[2][0] += w2.x*f0.x + w2.y*f0.y + w2.z*f0.z + w2.w*f0.w;
    acc[3][0] += w3.x*f0.x + w3.y*f0.y + w3.z*f0.z + w3.w*f0.w;
    acc[0][1] += w0.x*f1.x + w0.y*f1.y + w0.z*f1.z + w0.w*f1.w;
    acc[1][1] += w1.x*f1.x + w1.y*f1.y + w1.z*f1.z + w1.w*f1.w;
    acc[2][1] += w2.x*f1.x + w2.y*f1.y + w2.z*f1.z + w2.w*f1.w;
    acc[3][1] += w3.x*f1.x + w3.y*f1.y + w3.z*f1.z + w3.w*f1.w;
  }

  float mysum = 0.f;
#pragma unroll
  for (int bb = 0; bb < 2; bb++) {
    int bl = tb + 16 * bb;
    if (bl < cnt) {
      int bg = bucket[p0 + bl];
#pragma unroll
      for (int jj = 0; jj < 4; jj++) {
        int jr = tj + 16 * jj;
        float e = expf(acc[jj][bb] * invw[jr] * TINV);
        out0[(long long)bg * K1 + 1 + j0 + jr] = e;
        mysum += e;
      }
    }
  }
  float wsum = wredsum64(mysum);
  if ((t & 63) == 0) bs[t >> 6] = wsum;
  __syncthreads();
  if (t == 0) partials[pidx] = bs[0] + bs[1] + bs[2] + bs[3];
}

// ========== Stage D: redundant deterministic Z-reduce + out0 scale ==========
__global__ __launch_bounds__(256) void k_stageD(
    float* __restrict__ out0, const float* __restrict__ partials, int nPart,
    double factor, long long n4) {
  __shared__ double sd[256];
  int t = threadIdx.x;
  double s = 0.0;
  for (int i = t; i < nPart; i += 256) s += (double)partials[i];
  sd[t] = s;
  __syncthreads();
  for (int off = 128; off > 0; off >>= 1) {
    if (t < off) sd[t] += sd[t + off];
    __syncthreads();
  }
  float sc = (float)(factor / sd[0]);
  long long base = (long long)blockIdx.x * 256 + t;
  long long stride = (long long)gridDim.x * 256;
  for (long long i = base; i < n4; i += stride) {
    float4 v = ((float4*)out0)[i];
    v.x *= sc; v.y *= sc; v.z *= sc; v.w *= sc;
    ((float4*)out0)[i] = v;
  }
}

extern "C" void kernel_launch(void* const* d_in, const int* in_sizes, int n_in,
                              void* d_out, int out_size, void* d_ws,
                              size_t ws_size, hipStream_t stream) {
  const float* feat  = (const float*)d_in[0];
  const int*   label = (const int*)d_in[1];
  const float* mfg   = (const float*)d_in[5];
  const float* pg    = (const float*)d_in[6];
  const float* mfm   = (const float*)d_in[7];
  const float* pm    = (const float*)d_in[8];
  const int*   idxng = (const int*)d_in[9];
  const int*   idxpg = (const int*)d_in[10];
  const int*   idxnm = (const int*)d_in[11];
  const int*   idxpm = (const int*)d_in[12];
  float* outp = (float*)d_out;

  const int B = in_sizes[1];            // 512
  const int D = 128;
  const int K = in_sizes[9];            // 4096
  const int G = in_sizes[6];            // 131072
  const int M = in_sizes[8];            // 131072
  const int K1 = K + 1;

  const long long C0 = (long long)B * K1;
  const long long R = ((long long)out_size - C0) / (D + 1);
  const long long G0 = C0 + R * D;                 // gt base
  const long long cluTail = C0 + (R - B) * (long long)D;
  const long long gtTail = G0 + (R - B);

  const float* featn = outp + cluTail;

  char* wsb = (char*)d_ws;
  size_t o = 0;
  auto alloc = [&](size_t bytes) -> char* {
    char* p = wsb + o;
    o = (o + bytes + 255) & ~(size_t)255;
    return p;
  };
  const int simsGx = K / JT;                        // 64
  const int simsGy = B / BT + 1;                    // 17
  const int nPartSims = simsGx * simsGy;
  const int nPosBlk = (B * 64 + 255) / 256;         // 128
  float* partials = (float*)alloc(sizeof(float) * (nPartSims + nPosBlk));
  int* bucket = (int*)alloc(sizeof(int) * B);
  int* n0p = (int*)alloc(sizeof(int) * 4);
  const int NB = ((G > M ? G : M) + 255) / 256;     // 512 chunks of 256
  const int NG64 = NB * 4;                          // 2048 groups of 64
  int* cg64 = (int*)alloc(sizeof(int) * NG64);
  int* cm64 = (int*)alloc(sizeof(int) * NG64);
  (void)ws_size; (void)n_in;

  const int nFeatBlk = (B * 64 + 255) / 256;        // 128
  const int gridA = NB + nFeatBlk + nPosBlk + 1;
  const int nGatherBlk = 2 * NG64;                  // 4096
  const int gridB = nPartSims + nGatherBlk;
  const int gridD = 2048;

  k_stageA<<<gridA, 256, 0, stream>>>(
      feat, label, mfg, pg, mfm, pm, idxpg, idxpm,
      outp, cluTail, gtTail, bucket, n0p, cg64, cm64,
      partials + nPartSims, B, K1, G, M, NB, nFeatBlk, nPosBlk);

  k_stageB<<<gridB, 256, 0, stream>>>(
      featn, bucket, n0p, mfg, mfm, pg, pm, idxng, idxnm,
      cg64, cm64, outp, partials, outp, C0, G0,
      B, K, K1, G, M, NG64, simsGx, nPartSims);

  double factor = (double)B * (double)K1 / (double)G;
  k_stageD<<<gridD, 256, 0, stream>>>(
      outp, partials, nPartSims + nPosBlk, factor, C0 / 4);
}

// Round 6
// 53.669 us; speedup vs baseline: 1.1050x; 1.1050x over previous
//
#include <hip/hip_runtime.h>
#include <math.h>

// NCEAverage forward, MI355X — 3-dispatch pipeline, LDS-partitioned.
// d_out layout (float32):
//   [0, C0)               : out_feature_p_n (B x K+1), C0 = B*(K+1)
//   [C0, C0+R*128)        : feature_clu_all (R x 128)
//   [C0+R*128, C0+R*129)  : gt_clu_all (R)
// R derived on host from out_size.
//
// Stage A (small LDS): counts(256-chunk) | featn | pos | bucket
// Stage B (51.7KB LDS): sims tiles ONLY — LDS-throughput-bound by design
// Stage D (small LDS, full occupancy): per-chunk self-offset gather (4-row
//          unroll per half-wave) | redundant Z-reduce + out0 scale

#define TINV 14.2857142857142857f   // 1/0.07
#define JT 64
#define BT 32

__device__ __forceinline__ float wredsum64(float v) {
#pragma unroll
  for (int m = 32; m > 0; m >>= 1) v += __shfl_xor(v, m, 64);
  return v;
}

// ================= Stage A: counts | featn | pos | bucket ===================
__global__ __launch_bounds__(256) void k_stageA(
    const float* __restrict__ feat, const int* __restrict__ label,
    const float* __restrict__ mfg, const float* __restrict__ pg,
    const float* __restrict__ mfm, const float* __restrict__ pm,
    const int* __restrict__ idxpg, const int* __restrict__ idxpm,
    float* __restrict__ outp, long long cluTail, long long gtTail,
    int* __restrict__ bucket, int* __restrict__ n0p,
    int* __restrict__ cg, int* __restrict__ cm,
    float* __restrict__ posPartials,
    int B, int K1, int G, int M,
    int nCountBlk, int nFeatBlk, int nPosBlk) {
  int bid = blockIdx.x, t = threadIdx.x;

  if (bid < nCountBlk) {  // ---- per-256-chunk selection counts (both banks)
    __shared__ int s[8];
    int i = bid * 256 + t;
    int a = (i < G) && (pg[i] > 0.5f);
    int b = (i < M) && (pm[i] > 0.6f);
    unsigned long long ba = __ballot(a), bb = __ballot(b);
    int lane = t & 63, w = t >> 6;
    if (lane == 0) { s[w] = __popcll(ba); s[4 + w] = __popcll(bb); }
    __syncthreads();
    if (t == 0) cg[bid] = s[0] + s[1] + s[2] + s[3];
    if (t == 1) cm[bid] = s[4] + s[5] + s[6] + s[7];
    return;
  }
  bid -= nCountBlk;

  if (bid < nFeatBlk) {  // ---- normalize feat rows into d_out tail + gt
    int gid = bid * 256 + t;
    int w = gid >> 6, lane = gid & 63;
    if (w < B) {
      float2 v = ((const float2*)feat)[(long long)w * 64 + lane];
      float sq = wredsum64(v.x * v.x + v.y * v.y);
      float inv = rsqrtf(sq);
      ((float2*)(outp + cluTail))[(long long)w * 64 + lane] =
          make_float2(v.x * inv, v.y * inv);
      if (lane == 0) outp[gtTail + w] = (float)label[w];
    }
    return;
  }
  bid -= nFeatBlk;

  if (bid < nPosBlk) {  // ---- positives column (norms inline)
    __shared__ float ps[4];
    int gid = bid * 256 + t;
    int w = gid >> 6, lane = gid & 63, lw = t >> 6;
    float e = 0.f;
    if (w < B) {
      int lab = label[w];
      const float* bank = lab ? mfm : mfg;
      long long row = lab ? idxpm[0] : idxpg[0];
      float2 wv = ((const float2*)(bank + row * 128))[lane];
      float2 fv = ((const float2*)feat)[(long long)w * 64 + lane];
      float dot = wredsum64(fv.x * wv.x + fv.y * wv.y);
      float sqw = wredsum64(wv.x * wv.x + wv.y * wv.y);
      float sqf = wredsum64(fv.x * fv.x + fv.y * fv.y);
      e = expf(dot * rsqrtf(sqw) * rsqrtf(sqf) * TINV);
      if (lane == 0) outp[(long long)w * K1] = e;
    }
    if (lane == 0) ps[lw] = e;
    __syncthreads();
    if (t == 0) posPartials[bid] = ps[0] + ps[1] + ps[2] + ps[3];
    return;
  }

  // ---- bucket: stable partition of batch by label (B <= 512)
  {
    __shared__ int sc[512];
    int t2 = t + 256;
    int m0 = (t < B) ? (label[t] == 0 ? 1 : 0) : 0;
    int m1 = (t2 < B) ? (label[t2] == 0 ? 1 : 0) : 0;
    sc[t] = m0; sc[t2] = m1;
    __syncthreads();
    for (int off = 1; off < 512; off <<= 1) {
      int u0 = (t >= off) ? sc[t - off] : 0;
      int u1 = (t2 >= off) ? sc[t2 - off] : 0;
      __syncthreads();
      sc[t] += u0; sc[t2] += u1;
      __syncthreads();
    }
    int n0 = (B > 0) ? sc[B - 1] : 0;
    if (t < B) {
      int incl = sc[t];
      if (m0) bucket[incl - 1] = t; else bucket[n0 + t - incl] = t;
    }
    if (t2 < B) {
      int incl = sc[t2];
      if (m1) bucket[incl - 1] = t2; else bucket[n0 + t2 - incl] = t2;
    }
    if (t == 0) *n0p = n0;
  }
}

// ================= Stage B: sims tiles ONLY =================================
__global__ __launch_bounds__(256) void k_stageB(
    const float* __restrict__ featn, const int* __restrict__ bucket,
    const int* __restrict__ n0ptr,
    const float* __restrict__ mfg, const float* __restrict__ mfm,
    const int* __restrict__ idxng, const int* __restrict__ idxnm,
    float* __restrict__ out0, float* __restrict__ partials,
    int B, int K, int K1, int simsGx) {
  __shared__ float4 wl[JT][33];
  __shared__ float4 fl[BT][33];
  __shared__ float invw[JT];
  __shared__ float bs[4];
  int t = threadIdx.x;
  int pidx = (int)blockIdx.x;
  int bx = pidx % simsGx, by = pidx / simsGx;
  int n0 = *n0ptr;
  int nb0 = (n0 + BT - 1) / BT;
  int lab, p0, cnt;
  if (by < nb0) {
    lab = 0; p0 = by * BT; cnt = min(BT, n0 - p0);
  } else {
    int k = by - nb0; p0 = n0 + k * BT;
    int n1 = B - n0; cnt = min(BT, n1 - k * BT); lab = 1;
  }
  if (cnt <= 0) { if (t == 0) partials[pidx] = 0.f; return; }
  const float* bank = lab == 0 ? mfm : mfg;
  const int* idxN   = lab == 0 ? idxnm : idxng;
  int j0 = bx * JT;

#pragma unroll
  for (int q = 0; q < 8; q++) {
    int lin = q * 256 + t;
    int row = lin >> 5, col = lin & 31;
    long long srow = idxN[j0 + row];
    wl[row][col] = ((const float4*)(bank + srow * 128))[col];
  }
#pragma unroll
  for (int q = 0; q < 4; q++) {
    int lin = q * 256 + t;
    int row = lin >> 5, col = lin & 31;
    float4 v = make_float4(0.f, 0.f, 0.f, 0.f);
    if (row < cnt) {
      int bg = bucket[p0 + row];
      v = ((const float4*)(featn + (long long)bg * 128))[col];
    }
    fl[row][col] = v;
  }
  __syncthreads();

  {  // inline inverse norms of the staged w tile (4 threads per row)
    int r = t >> 2, q = t & 3;
    float ss = 0.f;
#pragma unroll
    for (int c = 0; c < 8; c++) {
      float4 v = wl[r][q * 8 + c];
      ss += v.x * v.x + v.y * v.y + v.z * v.z + v.w * v.w;
    }
    ss += __shfl_xor(ss, 1, 64);
    ss += __shfl_xor(ss, 2, 64);
    if (q == 0) invw[r] = rsqrtf(ss);
  }
  __syncthreads();

  int tj = t & 15, tb = t >> 4;
  float acc[4][2];
#pragma unroll
  for (int a = 0; a < 4; a++)
#pragma unroll
    for (int b = 0; b < 2; b++) acc[a][b] = 0.f;

#pragma unroll 4
  for (int i = 0; i < 32; i++) {
    float4 w0 = wl[tj][i];
    float4 w1 = wl[tj + 16][i];
    float4 w2 = wl[tj + 32][i];
    float4 w3 = wl[tj + 48][i];
    float4 f0 = fl[tb][i];
    float4 f1 = fl[tb + 16][i];
    acc[0][0] += w0.x*f0.x + w0.y*f0.y + w0.z*f0.z + w0.w*f0.w;
    acc[1][0] += w1.x*f0.x + w1.y*f0.y + w1.z*f0.z + w1.w*f0.w;
    acc[2][0] += w2.x*f0.x + w2.y*f0.y + w2.z*f0.z + w2.w*f0.w;
    acc[3][0] += w3.x*f0.x + w3.y*f0.y + w3.z*f0.z + w3.w*f0.w;
    acc[0][1] += w0.x*f1.x + w0.y*f1.y + w0.z*f1.z + w0.w*f1.w;
    acc[1][1] += w1.x*f1.x + w1.y*f1.y + w1.z*f1.z + w1.w*f1.w;
    acc[2][1] += w2.x*f1.x + w2.y*f1.y + w2.z*f1.z + w2.w*f1.w;
    acc[3][1] += w3.x*f1.x + w3.y*f1.y + w3.z*f1.z + w3.w*f1.w;
  }

  float mysum = 0.f;
#pragma unroll
  for (int bb = 0; bb < 2; bb++) {
    int bl = tb + 16 * bb;
    if (bl < cnt) {
      int bg = bucket[p0 + bl];
#pragma unroll
      for (int jj = 0; jj < 4; jj++) {
        int jr = tj + 16 * jj;
        float e = expf(acc[jj][bb] * invw[jr] * TINV);
        out0[(long long)bg * K1 + 1 + j0 + jr] = e;
        mysum += e;
      }
    }
  }
  float wsum = wredsum64(mysum);
  if ((t & 63) == 0) bs[t >> 6] = wsum;
  __syncthreads();
  if (t == 0) partials[pidx] = bs[0] + bs[1] + bs[2] + bs[3];
}

// ========= Stage D: gather (per-chunk, self-offset) | Z-reduce + scale ======
__global__ __launch_bounds__(256) void k_stageD(
    const float* __restrict__ mfg, const float* __restrict__ mfm,
    const float* __restrict__ pg, const float* __restrict__ pm,
    const int* __restrict__ cg, const int* __restrict__ cm,
    float* __restrict__ outp, long long cluBase, long long gtBase,
    int G, int M, int NB, int nGatherBlk,
    float* __restrict__ out0, const float* __restrict__ partials, int nPart,
    double factor, long long n4) {
  int t = threadIdx.x;

  if ((int)blockIdx.x < nGatherBlk) {
    // ---- gather: one block per (bank, 256-chunk); dest offset from counts.
    __shared__ int red[4];
    __shared__ int woff[4];
    __shared__ int selRow[256];
    int bid = blockIdx.x;
    int bankId = bid / NB;
    int cb = bid - bankId * NB;
    const float* probs = bankId ? pm : pg;
    const float* rows  = bankId ? mfm : mfg;
    float thr = bankId ? 0.6f : 0.5f;
    int Nelem = bankId ? M : G;
    int lane = t & 63, w = t >> 6;

    int j0 = t, j1 = t + 256;
    int s = 0;
    if (bankId == 0) {
      if (j0 < cb) s += cg[j0];
      if (j1 < cb && j1 < NB) s += cg[j1];
    } else {
      if (j0 < NB) s += cg[j0];
      if (j1 < NB) s += cg[j1];
      if (j0 < cb) s += cm[j0];
      if (j1 < cb && j1 < NB) s += cm[j1];
    }
#pragma unroll
    for (int m = 32; m > 0; m >>= 1) s += __shfl_xor(s, m, 64);
    if (lane == 0) red[w] = s;

    int i = cb * 256 + t;
    int f = (i < Nelem) && (probs[i] > thr);
    unsigned long long mb = __ballot(f);
    if (lane == 0) woff[w] = __popcll(mb);
    __syncthreads();

    long long off = (long long)red[0] + red[1] + red[2] + red[3];
    int pre = 0;
#pragma unroll
    for (int q = 0; q < 3; q++)
      if (q < w) pre += woff[q];
    int S = woff[0] + woff[1] + woff[2] + woff[3];
    unsigned long long below = lane ? ((~0ull) >> (64 - lane)) : 0ull;
    if (f) selRow[pre + __popcll(mb & below)] = i;
    __syncthreads();
    if (S == 0) return;

    float labv = (float)bankId;
    int hw = t >> 5, l = t & 31;
    for (int r0 = hw * 4; r0 < S; r0 += 32) {
      int r1 = r0 + 1, r2 = r0 + 2, r3 = r0 + 3;
      int s0 = selRow[r0];
      int s1 = selRow[r1 < S ? r1 : r0];
      int s2 = selRow[r2 < S ? r2 : r0];
      int s3 = selRow[r3 < S ? r3 : r0];
      float4 v0 = ((const float4*)(rows + (long long)s0 * 128))[l];
      float4 v1 = ((const float4*)(rows + (long long)s1 * 128))[l];
      float4 v2 = ((const float4*)(rows + (long long)s2 * 128))[l];
      float4 v3 = ((const float4*)(rows + (long long)s3 * 128))[l];
      float q0 = v0.x*v0.x + v0.y*v0.y + v0.z*v0.z + v0.w*v0.w;
      float q1 = v1.x*v1.x + v1.y*v1.y + v1.z*v1.z + v1.w*v1.w;
      float q2 = v2.x*v2.x + v2.y*v2.y + v2.z*v2.z + v2.w*v2.w;
      float q3 = v3.x*v3.x + v3.y*v3.y + v3.z*v3.z + v3.w*v3.w;
#pragma unroll
      for (int m = 16; m > 0; m >>= 1) {
        q0 += __shfl_xor(q0, m, 64);
        q1 += __shfl_xor(q1, m, 64);
        q2 += __shfl_xor(q2, m, 64);
        q3 += __shfl_xor(q3, m, 64);
      }
      float i0 = rsqrtf(q0), i1 = rsqrtf(q1), i2 = rsqrtf(q2), i3 = rsqrtf(q3);
      long long d0 = off + r0;
      ((float4*)(outp + cluBase + d0 * 128))[l] =
          make_float4(v0.x*i0, v0.y*i0, v0.z*i0, v0.w*i0);
      if (l == 0) outp[gtBase + d0] = labv;
      if (r1 < S) {
        long long d = off + r1;
        ((float4*)(outp + cluBase + d * 128))[l] =
            make_float4(v1.x*i1, v1.y*i1, v1.z*i1, v1.w*i1);
        if (l == 0) outp[gtBase + d] = labv;
      }
      if (r2 < S) {
        long long d = off + r2;
        ((float4*)(outp + cluBase + d * 128))[l] =
            make_float4(v2.x*i2, v2.y*i2, v2.z*i2, v2.w*i2);
        if (l == 0) outp[gtBase + d] = labv;
      }
      if (r3 < S) {
        long long d = off + r3;
        ((float4*)(outp + cluBase + d * 128))[l] =
            make_float4(v3.x*i3, v3.y*i3, v3.z*i3, v3.w*i3);
        if (l == 0) outp[gtBase + d] = labv;
      }
    }
    return;
  }

  // ---- redundant deterministic Z-reduce + out0 scale
  __shared__ double sd[256];
  double s = 0.0;
  for (int i = t; i < nPart; i += 256) s += (double)partials[i];
  sd[t] = s;
  __syncthreads();
  for (int off = 128; off > 0; off >>= 1) {
    if (t < off) sd[t] += sd[t + off];
    __syncthreads();
  }
  float sc = (float)(factor / sd[0]);
  long long base = (long long)((int)blockIdx.x - nGatherBlk) * 256 + t;
  long long stride = (long long)(gridDim.x - nGatherBlk) * 256;
  for (long long i = base; i < n4; i += stride) {
    float4 v = ((float4*)out0)[i];
    v.x *= sc; v.y *= sc; v.z *= sc; v.w *= sc;
    ((float4*)out0)[i] = v;
  }
}

extern "C" void kernel_launch(void* const* d_in, const int* in_sizes, int n_in,
                              void* d_out, int out_size, void* d_ws,
                              size_t ws_size, hipStream_t stream) {
  const float* feat  = (const float*)d_in[0];
  const int*   label = (const int*)d_in[1];
  const float* mfg   = (const float*)d_in[5];
  const float* pg    = (const float*)d_in[6];
  const float* mfm   = (const float*)d_in[7];
  const float* pm    = (const float*)d_in[8];
  const int*   idxng = (const int*)d_in[9];
  const int*   idxpg = (const int*)d_in[10];
  const int*   idxnm = (const int*)d_in[11];
  const int*   idxpm = (const int*)d_in[12];
  float* outp = (float*)d_out;

  const int B = in_sizes[1];            // 512
  const int D = 128;
  const int K = in_sizes[9];            // 4096
  const int G = in_sizes[6];            // 131072
  const int M = in_sizes[8];            // 131072
  const int K1 = K + 1;

  const long long C0 = (long long)B * K1;
  const long long R = ((long long)out_size - C0) / (D + 1);
  const long long G0 = C0 + R * D;                 // gt base
  const long long cluTail = C0 + (R - B) * (long long)D;
  const long long gtTail = G0 + (R - B);

  const float* featn = outp + cluTail;

  char* wsb = (char*)d_ws;
  size_t o = 0;
  auto alloc = [&](size_t bytes) -> char* {
    char* p = wsb + o;
    o = (o + bytes + 255) & ~(size_t)255;
    return p;
  };
  const int simsGx = K / JT;                        // 64
  const int simsGy = B / BT + 1;                    // 17
  const int nPartSims = simsGx * simsGy;            // 1088
  const int nPosBlk = (B * 64 + 255) / 256;         // 128
  float* partials = (float*)alloc(sizeof(float) * (nPartSims + nPosBlk));
  int* bucket = (int*)alloc(sizeof(int) * B);
  int* n0p = (int*)alloc(sizeof(int) * 4);
  const int NB = ((G > M ? G : M) + 255) / 256;     // 512
  int* cg = (int*)alloc(sizeof(int) * NB);
  int* cm = (int*)alloc(sizeof(int) * NB);
  (void)ws_size; (void)n_in;

  const int nFeatBlk = (B * 64 + 255) / 256;        // 128
  const int gridA = NB + nFeatBlk + nPosBlk + 1;
  const int gridB = nPartSims;
  const int nGatherBlk = 2 * NB;                    // 1024
  const int nScaleBlk = 1024;
  const int gridD = nGatherBlk + nScaleBlk;

  k_stageA<<<gridA, 256, 0, stream>>>(
      feat, label, mfg, pg, mfm, pm, idxpg, idxpm,
      outp, cluTail, gtTail, bucket, n0p, cg, cm,
      partials + nPartSims, B, K1, G, M, NB, nFeatBlk, nPosBlk);

  k_stageB<<<gridB, 256, 0, stream>>>(
      featn, bucket, n0p, mfg, mfm, idxng, idxnm,
      outp, partials, B, K, K1, simsGx);

  double factor = (double)B * (double)K1 / (double)G;
  k_stageD<<<gridD, 256, 0, stream>>>(
      mfg, mfm, pg, pm, cg, cm, outp, C0, G0, G, M, NB, nGatherBlk,
      outp, partials, nPartSims + nPosBlk, factor, C0 / 4);
}

// Round 7
// 44.547 us; speedup vs baseline: 1.3312x; 1.2048x over previous
//
#include <hip/hip_runtime.h>
#include <math.h>

// NCEAverage forward, MI355X — 3-dispatch pipeline, MFMA sims.
// d_out layout (float32):
//   [0, C0)               : out_feature_p_n (B x K+1), C0 = B*(K+1)
//   [C0, C0+R*128)        : feature_clu_all (R x 128)
//   [C0+R*128, C0+R*129)  : gt_clu_all (R)
// R derived on host from out_size.
//
// Stage A (small LDS): counts(256-chunk) | featn | pos | bucket
// Stage B (32KB LDS): bf16-MFMA sims, 64j x 64b tiles, XOR-swizzled LDS
// Stage D (small LDS): per-chunk self-offset gather | Z-reduce + out0 scale

#define TINV 14.2857142857142857f   // 1/0.07
#define JT 64                        // j tile
#define BT2 64                       // b tile

typedef __attribute__((ext_vector_type(8))) short bfrag;
typedef __attribute__((ext_vector_type(4))) float ffrag;

__device__ __forceinline__ float wredsum64(float v) {
#pragma unroll
  for (int m = 32; m > 0; m >>= 1) v += __shfl_xor(v, m, 64);
  return v;
}

__device__ __forceinline__ unsigned short f2bf(float x) {
  unsigned u = __float_as_uint(x);
  u += 0x7fffu + ((u >> 16) & 1u);   // RNE
  return (unsigned short)(u >> 16);
}

// swizzled LDS tile access: tile is [64 rows][256 bytes] bf16,
// byte offset within row XORed with (row&7)<<4  -> conflict-free b128 frags
__device__ __forceinline__ bfrag ldsread(const short* base, int row, int kb) {
  return *(const bfrag*)((const char*)base + row * 256 +
                         (kb ^ ((row & 7) << 4)));
}
__device__ __forceinline__ void ldswrite(short* base, int row, int kb,
                                         bfrag v) {
  *(bfrag*)((char*)base + row * 256 + (kb ^ ((row & 7) << 4))) = v;
}

// ================= Stage A: counts | featn | pos | bucket ===================
__global__ __launch_bounds__(256) void k_stageA(
    const float* __restrict__ feat, const int* __restrict__ label,
    const float* __restrict__ mfg, const float* __restrict__ pg,
    const float* __restrict__ mfm, const float* __restrict__ pm,
    const int* __restrict__ idxpg, const int* __restrict__ idxpm,
    float* __restrict__ outp, long long cluTail, long long gtTail,
    int* __restrict__ bucket, int* __restrict__ n0p,
    int* __restrict__ cg, int* __restrict__ cm,
    float* __restrict__ posPartials,
    int B, int K1, int G, int M,
    int nCountBlk, int nFeatBlk, int nPosBlk) {
  int bid = blockIdx.x, t = threadIdx.x;

  if (bid < nCountBlk) {  // ---- per-256-chunk selection counts (both banks)
    __shared__ int s[8];
    int i = bid * 256 + t;
    int a = (i < G) && (pg[i] > 0.5f);
    int b = (i < M) && (pm[i] > 0.6f);
    unsigned long long ba = __ballot(a), bb = __ballot(b);
    int lane = t & 63, w = t >> 6;
    if (lane == 0) { s[w] = __popcll(ba); s[4 + w] = __popcll(bb); }
    __syncthreads();
    if (t == 0) cg[bid] = s[0] + s[1] + s[2] + s[3];
    if (t == 1) cm[bid] = s[4] + s[5] + s[6] + s[7];
    return;
  }
  bid -= nCountBlk;

  if (bid < nFeatBlk) {  // ---- normalize feat rows into d_out tail + gt
    int gid = bid * 256 + t;
    int w = gid >> 6, lane = gid & 63;
    if (w < B) {
      float2 v = ((const float2*)feat)[(long long)w * 64 + lane];
      float sq = wredsum64(v.x * v.x + v.y * v.y);
      float inv = rsqrtf(sq);
      ((float2*)(outp + cluTail))[(long long)w * 64 + lane] =
          make_float2(v.x * inv, v.y * inv);
      if (lane == 0) outp[gtTail + w] = (float)label[w];
    }
    return;
  }
  bid -= nFeatBlk;

  if (bid < nPosBlk) {  // ---- positives column (norms inline)
    __shared__ float ps[4];
    int gid = bid * 256 + t;
    int w = gid >> 6, lane = gid & 63, lw = t >> 6;
    float e = 0.f;
    if (w < B) {
      int lab = label[w];
      const float* bank = lab ? mfm : mfg;
      long long row = lab ? idxpm[0] : idxpg[0];
      float2 wv = ((const float2*)(bank + row * 128))[lane];
      float2 fv = ((const float2*)feat)[(long long)w * 64 + lane];
      float dot = wredsum64(fv.x * wv.x + fv.y * wv.y);
      float sqw = wredsum64(wv.x * wv.x + wv.y * wv.y);
      float sqf = wredsum64(fv.x * fv.x + fv.y * fv.y);
      e = expf(dot * rsqrtf(sqw) * rsqrtf(sqf) * TINV);
      if (lane == 0) outp[(long long)w * K1] = e;
    }
    if (lane == 0) ps[lw] = e;
    __syncthreads();
    if (t == 0) posPartials[bid] = ps[0] + ps[1] + ps[2] + ps[3];
    return;
  }

  // ---- bucket: stable partition of batch by label (B <= 512)
  {
    __shared__ int sc[512];
    int t2 = t + 256;
    int m0 = (t < B) ? (label[t] == 0 ? 1 : 0) : 0;
    int m1 = (t2 < B) ? (label[t2] == 0 ? 1 : 0) : 0;
    sc[t] = m0; sc[t2] = m1;
    __syncthreads();
    for (int off = 1; off < 512; off <<= 1) {
      int u0 = (t >= off) ? sc[t - off] : 0;
      int u1 = (t2 >= off) ? sc[t2 - off] : 0;
      __syncthreads();
      sc[t] += u0; sc[t2] += u1;
      __syncthreads();
    }
    int n0 = (B > 0) ? sc[B - 1] : 0;
    if (t < B) {
      int incl = sc[t];
      if (m0) bucket[incl - 1] = t; else bucket[n0 + t - incl] = t;
    }
    if (t2 < B) {
      int incl = sc[t2];
      if (m1) bucket[incl - 1] = t2; else bucket[n0 + t2 - incl] = t2;
    }
    if (t == 0) *n0p = n0;
  }
}

// ================= Stage B: bf16-MFMA sims ==================================
// Block tile 64j x 64b, 4 waves (2x2), each wave 32j x 32b = 4 C-tiles x 4 K.
// A = featn rows (b, unit-norm), B = w rows (j); C[b][j], col(lane&15)=j.
__global__ __launch_bounds__(256) void k_stageB(
    const float* __restrict__ featn, const int* __restrict__ bucket,
    const int* __restrict__ n0ptr,
    const float* __restrict__ mfg, const float* __restrict__ mfm,
    const int* __restrict__ idxng, const int* __restrict__ idxnm,
    float* __restrict__ out0, float* __restrict__ partials,
    int B, int K, int K1, int simsGx) {
  __shared__ __align__(16) short wlds[64 * 128];
  __shared__ __align__(16) short flds[64 * 128];
  __shared__ float invw[64];
  __shared__ float bs[4];
  int t = threadIdx.x;
  int pidx = (int)blockIdx.x;
  int bx = pidx % simsGx, by = pidx / simsGx;
  int n0 = *n0ptr;
  int nb0 = (n0 + BT2 - 1) / BT2;
  int lab, p0, cnt;
  if (by < nb0) {
    lab = 0; p0 = by * BT2; cnt = min(BT2, n0 - p0);
  } else {
    int k = by - nb0; p0 = n0 + k * BT2;
    int n1 = B - n0; cnt = min(BT2, n1 - k * BT2); lab = 1;
  }
  if (cnt <= 0) { if (t == 0) partials[pidx] = 0.f; return; }
  const float* bank = lab == 0 ? mfm : mfg;
  const int* idxN   = lab == 0 ? idxnm : idxng;
  int j0 = bx * JT;

  // ---- stage w tile (fp32 -> bf16, swizzled) + row inv-norms
#pragma unroll
  for (int q = 0; q < 4; q++) {
    int slot = q * 256 + t;
    int row = slot >> 4, ch = slot & 15;   // ch = 8-elem chunk
    long long srow = idxN[j0 + row];
    const float4* gp = (const float4*)(bank + srow * 128 + ch * 8);
    float4 x0 = gp[0], x1 = gp[1];
    bfrag h;
    h[0] = (short)f2bf(x0.x); h[1] = (short)f2bf(x0.y);
    h[2] = (short)f2bf(x0.z); h[3] = (short)f2bf(x0.w);
    h[4] = (short)f2bf(x1.x); h[5] = (short)f2bf(x1.y);
    h[6] = (short)f2bf(x1.z); h[7] = (short)f2bf(x1.w);
    ldswrite(wlds, row, ch * 16, h);
    float s = x0.x*x0.x + x0.y*x0.y + x0.z*x0.z + x0.w*x0.w +
              x1.x*x1.x + x1.y*x1.y + x1.z*x1.z + x1.w*x1.w;
    s += __shfl_xor(s, 1, 64);
    s += __shfl_xor(s, 2, 64);
    s += __shfl_xor(s, 4, 64);
    s += __shfl_xor(s, 8, 64);
    if (ch == 0) invw[row] = rsqrtf(s);
  }
  // ---- stage f tile (bucket-gathered featn rows, zero-pad past cnt)
#pragma unroll
  for (int q = 0; q < 4; q++) {
    int slot = q * 256 + t;
    int row = slot >> 4, ch = slot & 15;
    bfrag h;
#pragma unroll
    for (int i = 0; i < 8; i++) h[i] = 0;
    if (row < cnt) {
      int bg = bucket[p0 + row];
      const float4* gp = (const float4*)(featn + (long long)bg * 128 + ch * 8);
      float4 x0 = gp[0], x1 = gp[1];
      h[0] = (short)f2bf(x0.x); h[1] = (short)f2bf(x0.y);
      h[2] = (short)f2bf(x0.z); h[3] = (short)f2bf(x0.w);
      h[4] = (short)f2bf(x1.x); h[5] = (short)f2bf(x1.y);
      h[6] = (short)f2bf(x1.z); h[7] = (short)f2bf(x1.w);
    }
    ldswrite(flds, row, ch * 16, h);
  }
  __syncthreads();

  // ---- MFMA: wave (wj, wb) handles j in [wj*32, +32), b in [wb*32, +32)
  int l = t & 63, wv = t >> 6;
  int wj = wv & 1, wb = wv >> 1;
  int colb = l & 15, kg = l >> 4;
  ffrag acc00 = {0.f, 0.f, 0.f, 0.f};
  ffrag acc01 = {0.f, 0.f, 0.f, 0.f};
  ffrag acc10 = {0.f, 0.f, 0.f, 0.f};
  ffrag acc11 = {0.f, 0.f, 0.f, 0.f};
#pragma unroll
  for (int ks = 0; ks < 4; ks++) {
    int kb = ks * 64 + kg * 16;
    bfrag a0 = ldsread(flds, wb * 32 + colb,      kb);
    bfrag a1 = ldsread(flds, wb * 32 + 16 + colb, kb);
    bfrag b0 = ldsread(wlds, wj * 32 + colb,      kb);
    bfrag b1 = ldsread(wlds, wj * 32 + 16 + colb, kb);
    acc00 = __builtin_amdgcn_mfma_f32_16x16x32_bf16(a0, b0, acc00, 0, 0, 0);
    acc01 = __builtin_amdgcn_mfma_f32_16x16x32_bf16(a0, b1, acc01, 0, 0, 0);
    acc10 = __builtin_amdgcn_mfma_f32_16x16x32_bf16(a1, b0, acc10, 0, 0, 0);
    acc11 = __builtin_amdgcn_mfma_f32_16x16x32_bf16(a1, b1, acc11, 0, 0, 0);
  }

  // ---- epilogue: e = exp(acc * invw[j] / T); C row=(l>>4)*4+reg -> b
  float mysum = 0.f;
  int rowg = l >> 4;
  auto epi = [&](const ffrag& A, int bt, int jt) {
    int bl = wb * 32 + bt * 16 + rowg * 4;
    int jl = wj * 32 + jt * 16 + colb;
    float iw = invw[jl];
#pragma unroll
    for (int r = 0; r < 4; r++) {
      int b2 = bl + r;
      if (b2 < cnt) {
        int bg = bucket[p0 + b2];
        float e = expf(A[r] * iw * TINV);
        out0[(long long)bg * K1 + 1 + j0 + jl] = e;
        mysum += e;
      }
    }
  };
  epi(acc00, 0, 0); epi(acc01, 0, 1); epi(acc10, 1, 0); epi(acc11, 1, 1);

  float wsum = wredsum64(mysum);
  if ((t & 63) == 0) bs[t >> 6] = wsum;
  __syncthreads();
  if (t == 0) partials[pidx] = bs[0] + bs[1] + bs[2] + bs[3];
}

// ========= Stage D: gather (per-chunk, self-offset) | Z-reduce + scale ======
__global__ __launch_bounds__(256) void k_stageD(
    const float* __restrict__ mfg, const float* __restrict__ mfm,
    const float* __restrict__ pg, const float* __restrict__ pm,
    const int* __restrict__ cg, const int* __restrict__ cm,
    float* __restrict__ outp, long long cluBase, long long gtBase,
    int G, int M, int NB, int nGatherBlk,
    float* __restrict__ out0, const float* __restrict__ partials, int nPart,
    double factor, long long n4) {
  int t = threadIdx.x;

  if ((int)blockIdx.x < nGatherBlk) {
    __shared__ int red[4];
    __shared__ int woff[4];
    __shared__ int selRow[256];
    int bid = blockIdx.x;
    int bankId = bid / NB;
    int cb = bid - bankId * NB;
    const float* probs = bankId ? pm : pg;
    const float* rows  = bankId ? mfm : mfg;
    float thr = bankId ? 0.6f : 0.5f;
    int Nelem = bankId ? M : G;
    int lane = t & 63, w = t >> 6;

    int j0 = t, j1 = t + 256;
    int s = 0;
    if (bankId == 0) {
      if (j0 < cb) s += cg[j0];
      if (j1 < cb && j1 < NB) s += cg[j1];
    } else {
      if (j0 < NB) s += cg[j0];
      if (j1 < NB) s += cg[j1];
      if (j0 < cb) s += cm[j0];
      if (j1 < cb && j1 < NB) s += cm[j1];
    }
#pragma unroll
    for (int m = 32; m > 0; m >>= 1) s += __shfl_xor(s, m, 64);
    if (lane == 0) red[w] = s;

    int i = cb * 256 + t;
    int f = (i < Nelem) && (probs[i] > thr);
    unsigned long long mb = __ballot(f);
    if (lane == 0) woff[w] = __popcll(mb);
    __syncthreads();

    long long off = (long long)red[0] + red[1] + red[2] + red[3];
    int pre = 0;
#pragma unroll
    for (int q = 0; q < 3; q++)
      if (q < w) pre += woff[q];
    int S = woff[0] + woff[1] + woff[2] + woff[3];
    unsigned long long below = lane ? ((~0ull) >> (64 - lane)) : 0ull;
    if (f) selRow[pre + __popcll(mb & below)] = i;
    __syncthreads();
    if (S == 0) return;

    float labv = (float)bankId;
    int hw = t >> 5, l = t & 31;
    for (int r0 = hw * 4; r0 < S; r0 += 32) {
      int r1 = r0 + 1, r2 = r0 + 2, r3 = r0 + 3;
      int s0 = selRow[r0];
      int s1 = selRow[r1 < S ? r1 : r0];
      int s2 = selRow[r2 < S ? r2 : r0];
      int s3 = selRow[r3 < S ? r3 : r0];
      float4 v0 = ((const float4*)(rows + (long long)s0 * 128))[l];
      float4 v1 = ((const float4*)(rows + (long long)s1 * 128))[l];
      float4 v2 = ((const float4*)(rows + (long long)s2 * 128))[l];
      float4 v3 = ((const float4*)(rows + (long long)s3 * 128))[l];
      float q0 = v0.x*v0.x + v0.y*v0.y + v0.z*v0.z + v0.w*v0.w;
      float q1 = v1.x*v1.x + v1.y*v1.y + v1.z*v1.z + v1.w*v1.w;
      float q2 = v2.x*v2.x + v2.y*v2.y + v2.z*v2.z + v2.w*v2.w;
      float q3 = v3.x*v3.x + v3.y*v3.y + v3.z*v3.z + v3.w*v3.w;
#pragma unroll
      for (int m = 16; m > 0; m >>= 1) {
        q0 += __shfl_xor(q0, m, 64);
        q1 += __shfl_xor(q1, m, 64);
        q2 += __shfl_xor(q2, m, 64);
        q3 += __shfl_xor(q3, m, 64);
      }
      float i0 = rsqrtf(q0), i1 = rsqrtf(q1), i2 = rsqrtf(q2), i3 = rsqrtf(q3);
      long long d0 = off + r0;
      ((float4*)(outp + cluBase + d0 * 128))[l] =
          make_float4(v0.x*i0, v0.y*i0, v0.z*i0, v0.w*i0);
      if (l == 0) outp[gtBase + d0] = labv;
      if (r1 < S) {
        long long d = off + r1;
        ((float4*)(outp + cluBase + d * 128))[l] =
            make_float4(v1.x*i1, v1.y*i1, v1.z*i1, v1.w*i1);
        if (l == 0) outp[gtBase + d] = labv;
      }
      if (r2 < S) {
        long long d = off + r2;
        ((float4*)(outp + cluBase + d * 128))[l] =
            make_float4(v2.x*i2, v2.y*i2, v2.z*i2, v2.w*i2);
        if (l == 0) outp[gtBase + d] = labv;
      }
      if (r3 < S) {
        long long d = off + r3;
        ((float4*)(outp + cluBase + d * 128))[l] =
            make_float4(v3.x*i3, v3.y*i3, v3.z*i3, v3.w*i3);
        if (l == 0) outp[gtBase + d] = labv;
      }
    }
    return;
  }

  // ---- redundant deterministic Z-reduce + out0 scale
  __shared__ double sd[256];
  double s = 0.0;
  for (int i = t; i < nPart; i += 256) s += (double)partials[i];
  sd[t] = s;
  __syncthreads();
  for (int off = 128; off > 0; off >>= 1) {
    if (t < off) sd[t] += sd[t + off];
    __syncthreads();
  }
  float sc = (float)(factor / sd[0]);
  long long base = (long long)((int)blockIdx.x - nGatherBlk) * 256 + t;
  long long stride = (long long)(gridDim.x - nGatherBlk) * 256;
  for (long long i = base; i < n4; i += stride) {
    float4 v = ((float4*)out0)[i];
    v.x *= sc; v.y *= sc; v.z *= sc; v.w *= sc;
    ((float4*)out0)[i] = v;
  }
}

extern "C" void kernel_launch(void* const* d_in, const int* in_sizes, int n_in,
                              void* d_out, int out_size, void* d_ws,
                              size_t ws_size, hipStream_t stream) {
  const float* feat  = (const float*)d_in[0];
  const int*   label = (const int*)d_in[1];
  const float* mfg   = (const float*)d_in[5];
  const float* pg    = (const float*)d_in[6];
  const float* mfm   = (const float*)d_in[7];
  const float* pm    = (const float*)d_in[8];
  const int*   idxng = (const int*)d_in[9];
  const int*   idxpg = (const int*)d_in[10];
  const int*   idxnm = (const int*)d_in[11];
  const int*   idxpm = (const int*)d_in[12];
  float* outp = (float*)d_out;

  const int B = in_sizes[1];            // 512
  const int D = 128;
  const int K = in_sizes[9];            // 4096
  const int G = in_sizes[6];            // 131072
  const int M = in_sizes[8];            // 131072
  const int K1 = K + 1;

  const long long C0 = (long long)B * K1;
  const long long R = ((long long)out_size - C0) / (D + 1);
  const long long G0 = C0 + R * D;                 // gt base
  const long long cluTail = C0 + (R - B) * (long long)D;
  const long long gtTail = G0 + (R - B);

  const float* featn = outp + cluTail;

  char* wsb = (char*)d_ws;
  size_t o = 0;
  auto alloc = [&](size_t bytes) -> char* {
    char* p = wsb + o;
    o = (o + bytes + 255) & ~(size_t)255;
    return p;
  };
  const int simsGx = K / JT;                        // 64
  const int simsGy = B / BT2 + 2;                   // 10 (covers label split)
  const int nPartSims = simsGx * simsGy;            // 640
  const int nPosBlk = (B * 64 + 255) / 256;         // 128
  float* partials = (float*)alloc(sizeof(float) * (nPartSims + nPosBlk));
  int* bucket = (int*)alloc(sizeof(int) * B);
  int* n0p = (int*)alloc(sizeof(int) * 4);
  const int NB = ((G > M ? G : M) + 255) / 256;     // 512
  int* cg = (int*)alloc(sizeof(int) * NB);
  int* cm = (int*)alloc(sizeof(int) * NB);
  (void)ws_size; (void)n_in;

  const int nFeatBlk = (B * 64 + 255) / 256;        // 128
  const int gridA = NB + nFeatBlk + nPosBlk + 1;
  const int gridB = nPartSims;
  const int nGatherBlk = 2 * NB;                    // 1024
  const int nScaleBlk = 1024;
  const int gridD = nGatherBlk + nScaleBlk;

  k_stageA<<<gridA, 256, 0, stream>>>(
      feat, label, mfg, pg, mfm, pm, idxpg, idxpm,
      outp, cluTail, gtTail, bucket, n0p, cg, cm,
      partials + nPartSims, B, K1, G, M, NB, nFeatBlk, nPosBlk);

  k_stageB<<<gridB, 256, 0, stream>>>(
      featn, bucket, n0p, mfg, mfm, idxng, idxnm,
      outp, partials, B, K, K1, simsGx);

  double factor = (double)B * (double)K1 / (double)G;
  k_stageD<<<gridD, 256, 0, stream>>>(
      mfg, mfm, pg, pm, cg, cm, outp, C0, G0, G, M, NB, nGatherBlk,
      outp, partials, nPartSims + nPosBlk, factor, C0 / 4);
}